// Round 8
// baseline (455.512 us; speedup 1.0000x reference)
//
#include <hip/hip_runtime.h>

// LocallyConnected2D: y[n,h,w] = relu(sum_{i,j} x[n,h+i,w+j]*W[h,w,i,j] + b[h,w])
// lane = batch n (N=64=wave). History:
//  R1: scalar (SMEM) weights -> lgkmcnt drains. R2/R3/R4: spills (local array /
//  hoist pressure / LDS-broadcast hoisting, WRITE 191-223MB). R5/R6: manual
//  pipeline + fences -> scratch catastrophe (1.8-3.7GB). R7: boring shape
//  (runtime r-loop, direct 9-tap VMEM loads) -> FIRST clean kernel: WRITE
//  63.5MB, VGPR 68, 282us. But VGPR=68 proves the scheduler serialized the 24
//  weight loads into batches (occupancy heuristic, blind to the LDS cap of
//  3 waves/SIMD) -> ~4 latency round-trips/iter instead of 1. And the R7
//  staging layout (n=t>>2) caused 8-way LDS write conflicts (2.06e7 cyc).
//  R8: (1) all 24 weight loads issued FIRST as named scalars, then 72 FMAs ->
//  one latency exposure/iter, ~115 VGPR live (fits 3 waves/SIMD cap of 170);
//  (2) staging reverted to R2-R6 lane-consecutive pattern (measured 0 confl).

#define H_IN 512
#define W_IN 512
#define H_OUT 504
#define W_OUT 504
#define W_T 8
#define H_T 4
#define TROWS (H_T + 8)      // 12 staged input rows
#define XF (TROWS * 1024)    // 12288 floats = 48 KB -> 3 blocks/CU

// 4-byte-aligned float4 for global loads at 4B-aligned addresses
typedef float f4u __attribute__((ext_vector_type(4), aligned(4)));

__launch_bounds__(256, 3)
__global__ void lc2d_kernel(const float* __restrict__ x,
                            const float* __restrict__ weight,
                            const float* __restrict__ bias,
                            float* __restrict__ out) {
    __shared__ float lds[XF];   // x tile: [row 0..11][plane 0..3][n 0..63][4]

    const int t    = threadIdx.x;
    const int lane = t & 63;          // batch index n
    const int wv   = t >> 6;          // wave 0..3

    const int h0 = blockIdx.y * H_T;
    const int w0 = blockIdx.x * W_T;

    // ---- stage x tile: wave wv stages plane wv, lane = n ----
    // LDS writes lane-consecutive 16B -> conflict-free (measured 0, R2-R6).
    {
        const float* gsrc = x + (size_t)lane * (H_IN * W_IN)
                              + (size_t)h0 * W_IN + w0 + wv * 4;
        float* ldst = &lds[wv * 256 + lane * 4];
        #pragma unroll
        for (int row = 0; row < TROWS; ++row) {
            const float4 v = *reinterpret_cast<const float4*>(gsrc + row * W_IN);
            *reinterpret_cast<float4*>(ldst + row * 1024) = v;
        }
    }
    __syncthreads();

    const int wvu = __builtin_amdgcn_readfirstlane(wv);
    const int h   = h0 + wvu;                      // this wave's output row

    float acc[W_T];
    {
        const float* bptr = bias + (size_t)h * W_OUT + w0;   // uniform s_load, once
        #pragma unroll
        for (int k = 0; k < W_T; ++k) acc[k] = bptr[k];
    }

    // wave-uniform weight base on the VMEM path (vzero); advances 9 floats/iter;
    // all 24 loads/iter are 13-bit immediate offsets off this one base.
    int vzero;
    asm volatile("v_mov_b32 %0, 0" : "=v"(vzero));
    const float* wp = weight + ((size_t)h * W_OUT + w0) * 81 + vzero;

    const float* xl = &lds[wv * 1024 + lane * 4];  // x row base; +1024/iter

    #pragma unroll 1
    for (int r = 0; r < 9; ++r) {
        // x row: 16 floats/lane via 4 conflict-free ds_read_b128
        float xr[16];
        #pragma unroll
        for (int c = 0; c < 4; ++c) {
            const float4 v = *reinterpret_cast<const float4*>(xl + c * 256);
            xr[4 * c + 0] = v.x; xr[4 * c + 1] = v.y;
            xr[4 * c + 2] = v.z; xr[4 * c + 3] = v.w;
        }

        // ---- ALL weight loads first (named -> registers, one vmcnt batch) ----
#define LOADK(k) \
        const f4u a##k = *reinterpret_cast<const f4u*>(wp + (k) * 81);      \
        const f4u b##k = *reinterpret_cast<const f4u*>(wp + (k) * 81 + 4);  \
        const float s##k = wp[(k) * 81 + 8];
        LOADK(0) LOADK(1) LOADK(2) LOADK(3)
        LOADK(4) LOADK(5) LOADK(6) LOADK(7)
#undef LOADK

        // ---- then all 72 FMAs ----
#define FMAK(k) \
        acc[k] = fmaf(a##k.x, xr[(k) + 0], acc[k]); \
        acc[k] = fmaf(a##k.y, xr[(k) + 1], acc[k]); \
        acc[k] = fmaf(a##k.z, xr[(k) + 2], acc[k]); \
        acc[k] = fmaf(a##k.w, xr[(k) + 3], acc[k]); \
        acc[k] = fmaf(b##k.x, xr[(k) + 4], acc[k]); \
        acc[k] = fmaf(b##k.y, xr[(k) + 5], acc[k]); \
        acc[k] = fmaf(b##k.z, xr[(k) + 6], acc[k]); \
        acc[k] = fmaf(b##k.w, xr[(k) + 7], acc[k]); \
        acc[k] = fmaf(s##k,   xr[(k) + 8], acc[k]);
        FMAK(0) FMAK(1) FMAK(2) FMAK(3)
        FMAK(4) FMAK(5) FMAK(6) FMAK(7)
#undef FMAK

        wp += 9;        // next tap-row
        xl += 1024;     // next x row
    }

    // ---- epilogue: ReLU + store (1 row x 8 floats per lane, 16B-aligned) ----
    float* o = out + (size_t)lane * (H_OUT * W_OUT) + (size_t)h * W_OUT + w0;
    float4 s;
    s.x = fmaxf(acc[0], 0.f); s.y = fmaxf(acc[1], 0.f);
    s.z = fmaxf(acc[2], 0.f); s.w = fmaxf(acc[3], 0.f);
    *reinterpret_cast<float4*>(o) = s;
    s.x = fmaxf(acc[4], 0.f); s.y = fmaxf(acc[5], 0.f);
    s.z = fmaxf(acc[6], 0.f); s.w = fmaxf(acc[7], 0.f);
    *reinterpret_cast<float4*>(o + 4) = s;
}

extern "C" void kernel_launch(void* const* d_in, const int* in_sizes, int n_in,
                              void* d_out, int out_size, void* d_ws, size_t ws_size,
                              hipStream_t stream) {
    const float* x      = (const float*)d_in[0];
    const float* weight = (const float*)d_in[1];
    const float* bias   = (const float*)d_in[2];
    float* out          = (float*)d_out;

    dim3 grid(W_OUT / W_T, H_OUT / H_T);   // 63 x 126
    dim3 block(256);
    lc2d_kernel<<<grid, block, 0, stream>>>(x, weight, bias, out);
}